// Round 1
// baseline (445.525 us; speedup 1.0000x reference)
//
#include <hip/hip_runtime.h>
#include <hip/hip_bf16.h>

#define B_ 16
#define CIN_ 512
#define COUT_ 512
#define SDIM_ 512
#define HIN_ 32
#define WIN_ 32
#define HOUT_ 64
#define WOUT_ 64

#define LIN_SCALE_C 0.044194173824159216f
#define CONV_SCALE_C 0.014731391274719742f

typedef short short8 __attribute__((ext_vector_type(8)));
typedef float f32x4 __attribute__((ext_vector_type(4)));

typedef const __attribute__((address_space(1))) void* gptr_t;
typedef __attribute__((address_space(3))) void* sptr_t;

__device__ __forceinline__ void glds16(const void* g, void* l) {
    __builtin_amdgcn_global_load_lds((gptr_t)g, (sptr_t)l, 16, 0, 0);
}

// ---------------- style: s[b,i] = LIN_SCALE * dot(w[b,:], lin_w[i,:]) + lin_b[i]
__global__ void style_kernel(const float* __restrict__ w, const float* __restrict__ lin_w,
                             const float* __restrict__ lin_b, float* __restrict__ s) {
    const int i = blockIdx.x * 256 + threadIdx.x;   // 0..511
    const int b = blockIdx.y;
    const float* wr = w + b * SDIM_;
    const float* lw = lin_w + i * SDIM_;
    float acc = 0.f;
    #pragma unroll 4
    for (int j = 0; j < SDIM_; ++j) acc += wr[j] * lw[j];
    s[b * CIN_ + i] = acc * LIN_SCALE_C + lin_b[i];
}

// ---------------- weights: w2[o][kk][i] = bf16(conv_w[o][i][kk]*CS); wsq[o][i] = sum_kk wk^2
__global__ void prep_weights(const float* __restrict__ conv_w, __hip_bfloat16* __restrict__ w2,
                             float* __restrict__ wsq, float* __restrict__ zbuf) {
    const int o = blockIdx.x;
    for (int i = threadIdx.x; i < CIN_; i += 256) {
        const float* src = conv_w + (o * CIN_ + i) * 9;
        float ss = 0.f;
        #pragma unroll
        for (int kk = 0; kk < 9; ++kk) {
            float v = src[kk] * CONV_SCALE_C;
            ss += v * v;
            w2[o * 4608 + kk * 512 + i] = __float2bfloat16(v);
        }
        wsq[o * CIN_ + i] = ss;
    }
    if (blockIdx.x == 0 && threadIdx.x < 64) zbuf[threadIdx.x] = 0.f;  // zero page for OOB halo
}

// ---------------- demod[b,o] = 1/sqrt(sum_i wsq[o,i]*s[b,i]^2 + eps)
__global__ void demod_kernel(const float* __restrict__ wsq, const float* __restrict__ s,
                             float* __restrict__ demod) {
    const int o = blockIdx.x * 256 + threadIdx.x;
    const int b = blockIdx.y;
    const float* sr = s + b * CIN_;
    const float* wr = wsq + o * CIN_;
    float acc = 0.f;
    #pragma unroll 4
    for (int i = 0; i < CIN_; ++i) { float sv = sr[i]; acc += wr[i] * sv * sv; }
    demod[b * COUT_ + o] = 1.0f / sqrtf(acc + 1e-8f);
}

// ---------------- bilinear 2x upsample + modulate, NCHW fp32 -> NHWC bf16
// half-pixel centers: out ho -> src f = ho/2 - 0.25 ; 2-tap {0.25,0.75}, edge-clamped
__global__ void upsample_mod_kernel(const float* __restrict__ x, const float* __restrict__ s,
                                    __hip_bfloat16* __restrict__ xq) {
    __shared__ float xs[10 * 32 * 33];  // [row 10][col 32][ch 33-padded]
    const int ht = blockIdx.x;          // 0..3  -> 16 output rows
    const int ct = blockIdx.y;          // 0..15 -> 32 channels
    const int b  = blockIdx.z;
    const int tid = threadIdx.x;
    const int ho0 = ht * 16, h0 = ht * 8, c0 = ct * 32;

    for (int idx = tid; idx < 10240; idx += 256) {
        int ch = idx / 320; int rem = idx - ch * 320;
        int rr = rem >> 5;  int col = rem & 31;
        int srow = h0 - 1 + rr; srow = min(max(srow, 0), 31);
        xs[(rr * 32 + col) * 33 + ch] = x[((b * CIN_ + c0 + ch) * HIN_ + srow) * WIN_ + col];
    }
    __syncthreads();

    for (int e = tid; e < 32768; e += 256) {
        int c = e & 31; int rest = e >> 5; int wo = rest & 63; int hr = rest >> 6;
        int ri0 = (hr + (hr & 1)) >> 1;                 // lo row tap (xs row index)
        float wlo_h = (hr & 1) ? 0.75f : 0.25f;
        int clo = (wo - 2 + (wo & 1)) >> 1;             // lo col tap (input col)
        float wlo_w = (wo & 1) ? 0.75f : 0.25f;
        int chi = min(clo + 1, 31); clo = max(clo, 0);
        float v0 = xs[(ri0 * 32 + clo) * 33 + c];
        float v1 = xs[(ri0 * 32 + chi) * 33 + c];
        float v2 = xs[((ri0 + 1) * 32 + clo) * 33 + c];
        float v3 = xs[((ri0 + 1) * 32 + chi) * 33 + c];
        float rlo = wlo_w * v0 + (1.f - wlo_w) * v1;
        float rhi = wlo_w * v2 + (1.f - wlo_w) * v3;
        float val = (wlo_h * rlo + (1.f - wlo_h) * rhi) * s[b * CIN_ + c0 + c];
        xq[(((b * HOUT_ + ho0 + hr) * WOUT_) + wo) * CIN_ + c0 + c] = __float2bfloat16(val);
    }
}

// ---------------- implicit-GEMM conv: per batch D[cout][pixel], M=512 N=4096 K=4608
// tile 128x128 (BK=32), 4 waves (2x2), each wave 64x64 via 4x4 mfma_16x16x32 frags
__launch_bounds__(256)
__global__ void conv_kernel(const __hip_bfloat16* __restrict__ xq,
                            const __hip_bfloat16* __restrict__ w2,
                            const float* __restrict__ demod,
                            const float* __restrict__ noise,
                            const float* __restrict__ nw_p,
                            float* __restrict__ out,
                            const __hip_bfloat16* __restrict__ zbuf) {
    __shared__ __attribute__((aligned(16))) __hip_bfloat16 As[128 * 32];  // [cout][ch]
    __shared__ __attribute__((aligned(16))) __hip_bfloat16 Bs[128 * 32];  // [pixel][ch]

    const int bid = blockIdx.x;
    const int b   = bid >> 7;          // 128 tiles per batch
    const int rem = bid & 127;
    const int mt  = rem >> 5;          // 0..3   cout tile
    const int nt  = rem & 31;          // 0..31  pixel tile (2 rows x 64 cols)
    const int o0  = mt * 128;
    const int r0  = nt * 2;
    const int p0  = nt * 128;

    const int tid  = threadIdx.x;
    const int lane = tid & 63;
    const int wave = tid >> 6;
    const int wr = wave >> 1, wc = wave & 1;

    // staging coords: 4 threads per row (64B = 32 bf16), 2 issues each for A and B
    const int arow = tid >> 2;          // 0..63
    const int kcol = (tid & 3) * 8;     // bf16 elements
    const __hip_bfloat16* a_src0 = w2 + (o0 + arow) * 4608 + kcol;
    const __hip_bfloat16* a_src1 = a_src0 + 64 * 4608;
    __hip_bfloat16* a_dst0 = As + tid * 8;
    __hip_bfloat16* a_dst1 = As + 2048 + tid * 8;
    const int jc = tid >> 2;            // pixel col 0..63 (issue0: row r0, issue1: row r0+1)
    __hip_bfloat16* b_dst0 = Bs + tid * 8;
    __hip_bfloat16* b_dst1 = Bs + 2048 + tid * 8;

    f32x4 acc[4][4] = {};

    const int lrow = lane & 15;
    const int koff = (lane >> 4) * 8;

    #pragma unroll 1
    for (int kk = 0; kk < 9; ++kk) {
        const int dh = kk / 3 - 1, dw = kk % 3 - 1;
        const int cc  = jc + dw;
        const int rr0 = r0 + dh;
        const int rr1 = rr0 + 1;
        const bool ccv = (cc >= 0) && (cc < 64);
        const bool v0 = ccv && (rr0 >= 0) && (rr0 < 64);
        const bool v1 = ccv && (rr1 >= 0) && (rr1 < 64);
        const __hip_bfloat16* bsrc0 = v0 ? xq + ((b * 64 + rr0) * 64 + cc) * 512 + kcol : zbuf;
        const __hip_bfloat16* bsrc1 = v1 ? xq + ((b * 64 + rr1) * 64 + cc) * 512 + kcol : zbuf;
        const int st0 = v0 ? 32 : 0, st1 = v1 ? 32 : 0;
        const __hip_bfloat16* asrc0 = a_src0 + kk * 512;
        const __hip_bfloat16* asrc1 = a_src1 + kk * 512;

        #pragma unroll
        for (int it = 0; it < 16; ++it) {
            glds16(asrc0 + it * 32, a_dst0);
            glds16(asrc1 + it * 32, a_dst1);
            glds16(bsrc0 + it * st0, b_dst0);
            glds16(bsrc1 + it * st1, b_dst1);
            __syncthreads();   // drains vmcnt -> staged data visible

            short8 a[4], bf[4];
            #pragma unroll
            for (int mi = 0; mi < 4; ++mi)
                a[mi] = *(const short8*)(As + (wr * 64 + mi * 16 + lrow) * 32 + koff);
            #pragma unroll
            for (int ni = 0; ni < 4; ++ni)
                bf[ni] = *(const short8*)(Bs + (wc * 64 + ni * 16 + lrow) * 32 + koff);
            #pragma unroll
            for (int mi = 0; mi < 4; ++mi)
                #pragma unroll
                for (int ni = 0; ni < 4; ++ni)
                    acc[mi][ni] = __builtin_amdgcn_mfma_f32_16x16x32_bf16(a[mi], bf[ni], acc[mi][ni], 0, 0, 0);
            __syncthreads();   // all reads done before next-iter staging overwrites
        }
    }

    // epilogue: demod * acc + nw*noise, leaky-relu * sqrt(2)
    const float nwv = nw_p[0];
    const int colp = lane & 15;
    const int rgrp = (lane >> 4) * 4;
    float nz[4];
    #pragma unroll
    for (int ni = 0; ni < 4; ++ni)
        nz[ni] = noise[b * 4096 + p0 + wc * 64 + ni * 16 + colp] * nwv;
    #pragma unroll
    for (int mi = 0; mi < 4; ++mi) {
        const int obase = o0 + wr * 64 + mi * 16 + rgrp;
        float dm[4];
        #pragma unroll
        for (int j = 0; j < 4; ++j) dm[j] = demod[b * COUT_ + obase + j];
        #pragma unroll
        for (int ni = 0; ni < 4; ++ni) {
            const int pix = p0 + wc * 64 + ni * 16 + colp;
            #pragma unroll
            for (int j = 0; j < 4; ++j) {
                float v = acc[mi][ni][j] * dm[j] + nz[ni];
                v = (v >= 0.f ? v : 0.2f * v) * 1.4142135623730951f;
                out[(size_t)(b * COUT_ + obase + j) * 4096 + pix] = v;
            }
        }
    }
}

extern "C" void kernel_launch(void* const* d_in, const int* in_sizes, int n_in,
                              void* d_out, int out_size, void* d_ws, size_t ws_size,
                              hipStream_t stream) {
    const float* x      = (const float*)d_in[0];
    const float* w      = (const float*)d_in[1];
    const float* noise  = (const float*)d_in[2];
    const float* lin_w  = (const float*)d_in[3];
    const float* lin_b  = (const float*)d_in[4];
    const float* conv_w = (const float*)d_in[5];
    const float* nw     = (const float*)d_in[6];
    float* out = (float*)d_out;

    char* ws = (char*)d_ws;
    __hip_bfloat16* xq = (__hip_bfloat16*)ws;                    // 67108864 B (NHWC bf16)
    __hip_bfloat16* w2 = (__hip_bfloat16*)(ws + 67108864);       //  4718592 B
    float* s     = (float*)(ws + 71827456);                      //    32768 B
    float* demod = (float*)(ws + 71860224);                      //    32768 B
    float* wsq   = (float*)(ws + 71892992);                      //  1048576 B
    float* zbuf  = (float*)(ws + 72941568);                      //      256 B (zero page)

    style_kernel<<<dim3(2, 16), 256, 0, stream>>>(w, lin_w, lin_b, s);
    prep_weights<<<512, 256, 0, stream>>>(conv_w, w2, wsq, zbuf);
    demod_kernel<<<dim3(2, 16), 256, 0, stream>>>(wsq, s, demod);
    upsample_mod_kernel<<<dim3(4, 16, 16), 256, 0, stream>>>(x, s, xq);
    conv_kernel<<<2048, 256, 0, stream>>>(xq, w2, demod, noise, nw, out,
                                          (const __hip_bfloat16*)zbuf);
}

// Round 2
// 352.454 us; speedup vs baseline: 1.2641x; 1.2641x over previous
//
#include <hip/hip_runtime.h>
#include <hip/hip_bf16.h>

#define B_ 16
#define CIN_ 512
#define COUT_ 512
#define SDIM_ 512
#define HIN_ 32
#define WIN_ 32
#define HOUT_ 64
#define WOUT_ 64

#define LIN_SCALE_C 0.044194173824159216f
#define CONV_SCALE_C 0.014731391274719742f

typedef short short8 __attribute__((ext_vector_type(8)));
typedef float f32x4 __attribute__((ext_vector_type(4)));

typedef const __attribute__((address_space(1))) void* gptr_t;
typedef __attribute__((address_space(3))) void* sptr_t;

__device__ __forceinline__ void glds16(const void* g, void* l) {
    __builtin_amdgcn_global_load_lds((gptr_t)g, (sptr_t)l, 16, 0, 0);
}

// ---------------- style: s[b,i] = LIN_SCALE * dot(w[b,:], lin_w[i,:]) + lin_b[i]
__global__ void style_kernel(const float* __restrict__ w, const float* __restrict__ lin_w,
                             const float* __restrict__ lin_b, float* __restrict__ s) {
    const int i = blockIdx.x * 256 + threadIdx.x;   // 0..511
    const int b = blockIdx.y;
    const float* wr = w + b * SDIM_;
    const float* lw = lin_w + i * SDIM_;
    float acc = 0.f;
    #pragma unroll 4
    for (int j = 0; j < SDIM_; ++j) acc += wr[j] * lw[j];
    s[b * CIN_ + i] = acc * LIN_SCALE_C + lin_b[i];
}

// ---------------- weights: w2[o][kk][i] = bf16(conv_w[o][i][kk]*CS); wsq[o][i] = sum_kk wk^2
__global__ void prep_weights(const float* __restrict__ conv_w, __hip_bfloat16* __restrict__ w2,
                             float* __restrict__ wsq, float* __restrict__ zbuf) {
    const int o = blockIdx.x;
    for (int i = threadIdx.x; i < CIN_; i += 256) {
        const float* src = conv_w + (o * CIN_ + i) * 9;
        float ss = 0.f;
        #pragma unroll
        for (int kk = 0; kk < 9; ++kk) {
            float v = src[kk] * CONV_SCALE_C;
            ss += v * v;
            w2[o * 4608 + kk * 512 + i] = __float2bfloat16(v);
        }
        wsq[o * CIN_ + i] = ss;
    }
    if (blockIdx.x == 0 && threadIdx.x < 64) zbuf[threadIdx.x] = 0.f;  // zero page for OOB halo
}

// ---------------- demod[b,o] = 1/sqrt(sum_i wsq[o,i]*s[b,i]^2 + eps)
__global__ void demod_kernel(const float* __restrict__ wsq, const float* __restrict__ s,
                             float* __restrict__ demod) {
    const int o = blockIdx.x * 256 + threadIdx.x;
    const int b = blockIdx.y;
    const float* sr = s + b * CIN_;
    const float* wr = wsq + o * CIN_;
    float acc = 0.f;
    #pragma unroll 4
    for (int i = 0; i < CIN_; ++i) { float sv = sr[i]; acc += wr[i] * sv * sv; }
    demod[b * COUT_ + o] = 1.0f / sqrtf(acc + 1e-8f);
}

// ---------------- bilinear 2x upsample + modulate, NCHW fp32 -> NHWC bf16
__global__ void upsample_mod_kernel(const float* __restrict__ x, const float* __restrict__ s,
                                    __hip_bfloat16* __restrict__ xq) {
    __shared__ float xs[10 * 32 * 33];  // [row 10][col 32][ch 33-padded]
    const int ht = blockIdx.x;          // 0..3  -> 16 output rows
    const int ct = blockIdx.y;          // 0..15 -> 32 channels
    const int b  = blockIdx.z;
    const int tid = threadIdx.x;
    const int ho0 = ht * 16, h0 = ht * 8, c0 = ct * 32;

    for (int idx = tid; idx < 10240; idx += 256) {
        int ch = idx / 320; int rem = idx - ch * 320;
        int rr = rem >> 5;  int col = rem & 31;
        int srow = h0 - 1 + rr; srow = min(max(srow, 0), 31);
        xs[(rr * 32 + col) * 33 + ch] = x[((b * CIN_ + c0 + ch) * HIN_ + srow) * WIN_ + col];
    }
    __syncthreads();

    for (int e = tid; e < 32768; e += 256) {
        int c = e & 31; int rest = e >> 5; int wo = rest & 63; int hr = rest >> 6;
        int ri0 = (hr + (hr & 1)) >> 1;
        float wlo_h = (hr & 1) ? 0.75f : 0.25f;
        int clo = (wo - 2 + (wo & 1)) >> 1;
        float wlo_w = (wo & 1) ? 0.75f : 0.25f;
        int chi = min(clo + 1, 31); clo = max(clo, 0);
        float v0 = xs[(ri0 * 32 + clo) * 33 + c];
        float v1 = xs[(ri0 * 32 + chi) * 33 + c];
        float v2 = xs[((ri0 + 1) * 32 + clo) * 33 + c];
        float v3 = xs[((ri0 + 1) * 32 + chi) * 33 + c];
        float rlo = wlo_w * v0 + (1.f - wlo_w) * v1;
        float rhi = wlo_w * v2 + (1.f - wlo_w) * v3;
        float val = (wlo_h * rlo + (1.f - wlo_h) * rhi) * s[b * CIN_ + c0 + c];
        xq[(((b * HOUT_ + ho0 + hr) * WOUT_) + wo) * CIN_ + c0 + c] = __float2bfloat16(val);
    }
}

// ---------------- implicit-GEMM conv, 256x256 tile, BK=32, 4-deep LDS ring, counted vmcnt
// per batch: C[512][4096] = w2[512][4608] x B[4608][4096]; 144 K-tiles of 32
__global__ __launch_bounds__(512)
void conv_kernel(const __hip_bfloat16* __restrict__ xq,
                 const __hip_bfloat16* __restrict__ w2,
                 const float* __restrict__ demod,
                 const float* __restrict__ noise,
                 const float* __restrict__ nw_p,
                 float* __restrict__ out,
                 const __hip_bfloat16* __restrict__ zbuf) {
    extern __shared__ __hip_bfloat16 smem[];
    __hip_bfloat16* As = smem;           // 4 slots x [256][32] = 4 x 8192 elems (64 KB)
    __hip_bfloat16* Bs = smem + 32768;   // 4 slots x [256][32]                  (64 KB)

    // block decode + XCD-aware swizzle (512 blocks, %8==0 -> simple form is bijective)
    const int bid = blockIdx.x;
    const int swz = (bid & 7) * 64 + (bid >> 3);
    const int b  = swz >> 5;          // 16 batches
    const int mt = (swz >> 4) & 1;    // 2 cout tiles
    const int nt = swz & 15;          // 16 pixel tiles (4 rows x 64 cols each)
    const int o0 = mt * 256;
    const int p0 = nt * 256;

    const int tid  = threadIdx.x;
    const int lane = tid & 63;
    const int wave = tid >> 6;
    const int wm = wave >> 2, wn = wave & 3;   // 2M x 4N waves, each 128x64 out

    // ---- staging coords: 4 threads per row (64B), rows 0..127 per half
    const int srow = tid >> 2;            // 0..127
    const int schk = (tid & 3) * 8;       // element offset within 32-ch row
    const int aoff = (o0 + srow) * 4608 + schk;          // + h*128*4608 + u*32
    const int brow_lo = nt * 4 + (srow >> 6);            // + h*2 + dh
    const int bcol = srow & 63;
    const int sdst = tid * 8;             // + slot*8192 + h*4096 (elements)

    // ---- frag read offsets (elements, within slot)
    const int ard = (wm * 128 + (lane & 15)) * 32 + (lane >> 4) * 8;  // + m*512
    const int brd = (wn * 64 + (lane & 15)) * 32 + (lane >> 4) * 8;   // + n*512

    f32x4 acc[8][4] = {};

    #define STAGE_A(u, h) \
        glds16(w2 + aoff + (h) * 589824 + (u) * 32, As + (((u) & 3) << 13) + ((h) << 12) + sdst)
    #define STAGE_B(u, h, dh, dw, i0) do { \
        int rr_ = brow_lo + (h) * 2 + (dh); \
        int cc_ = bcol + (dw); \
        bool v_ = ((unsigned)rr_ < 64u) && ((unsigned)cc_ < 64u); \
        const __hip_bfloat16* src_ = v_ ? xq + ((b * 64 + rr_) * 64 + cc_) * 512 + (i0) + schk : zbuf; \
        glds16(src_, Bs + (((u) & 3) << 13) + ((h) << 12) + sdst); \
    } while (0)

    // prologue: stage tiles 0 and 1 (both in kk=0: dh=dw=-1)
    STAGE_A(0, 0); STAGE_A(0, 1); STAGE_B(0, 0, -1, -1, 0);  STAGE_B(0, 1, -1, -1, 0);
    STAGE_A(1, 0); STAGE_A(1, 1); STAGE_B(1, 0, -1, -1, 32); STAGE_B(1, 1, -1, -1, 32);
    asm volatile("s_waitcnt vmcnt(4)" ::: "memory");   // tile 0 fully landed
    __builtin_amdgcn_s_barrier();

    #pragma unroll 4
    for (int t = 0; t < 144; ++t) {
        const int slot = (t & 3) << 13;

        short8 a[8], bf[4];
        #pragma unroll
        for (int m = 0; m < 8; ++m)
            a[m] = *(const short8*)(As + slot + ard + m * 512);
        #pragma unroll
        for (int n = 0; n < 4; ++n)
            bf[n] = *(const short8*)(Bs + slot + brd + n * 512);

        const int u = t + 2;
        if (u < 144) {
            const int kk = u >> 4;
            const int i0 = (u & 15) << 5;
            const int kd = (kk * 11) >> 5;       // kk/3
            const int dh = kd - 1, dw = kk - kd * 3 - 1;
            STAGE_A(u, 0); STAGE_A(u, 1);
            STAGE_B(u, 0, dh, dw, i0); STAGE_B(u, 1, dh, dw, i0);
        }

        // counted wait: forces tile t+1 (staged last iter) complete; leaves this
        // iter's 4 stages (tile t+2) in flight. Tail: drain.
        if (t < 142) asm volatile("s_waitcnt vmcnt(4)" ::: "memory");
        else         asm volatile("s_waitcnt vmcnt(0)" ::: "memory");
        __builtin_amdgcn_s_barrier();

        __builtin_amdgcn_s_setprio(1);
        #pragma unroll
        for (int m = 0; m < 8; ++m)
            #pragma unroll
            for (int n = 0; n < 4; ++n)
                acc[m][n] = __builtin_amdgcn_mfma_f32_16x16x32_bf16(a[m], bf[n], acc[m][n], 0, 0, 0);
        __builtin_amdgcn_s_setprio(0);
    }
    #undef STAGE_A
    #undef STAGE_B

    // epilogue: demod * acc + nw*noise, leaky-relu * sqrt(2)
    const float nwv = nw_p[0];
    const int colp = lane & 15;
    const int rgrp = (lane >> 4) * 4;
    float nz[4];
    #pragma unroll
    for (int ni = 0; ni < 4; ++ni)
        nz[ni] = noise[b * 4096 + p0 + wn * 64 + ni * 16 + colp] * nwv;
    #pragma unroll
    for (int mi = 0; mi < 8; ++mi) {
        const int obase = o0 + wm * 128 + mi * 16 + rgrp;
        float dm[4];
        #pragma unroll
        for (int j = 0; j < 4; ++j) dm[j] = demod[b * COUT_ + obase + j];
        #pragma unroll
        for (int ni = 0; ni < 4; ++ni) {
            const int pix = p0 + wn * 64 + ni * 16 + colp;
            #pragma unroll
            for (int j = 0; j < 4; ++j) {
                float v = acc[mi][ni][j] * dm[j] + nz[ni];
                v = (v >= 0.f ? v : 0.2f * v) * 1.4142135623730951f;
                out[(b * COUT_ + obase + j) * 4096 + pix] = v;
            }
        }
    }
}

extern "C" void kernel_launch(void* const* d_in, const int* in_sizes, int n_in,
                              void* d_out, int out_size, void* d_ws, size_t ws_size,
                              hipStream_t stream) {
    const float* x      = (const float*)d_in[0];
    const float* w      = (const float*)d_in[1];
    const float* noise  = (const float*)d_in[2];
    const float* lin_w  = (const float*)d_in[3];
    const float* lin_b  = (const float*)d_in[4];
    const float* conv_w = (const float*)d_in[5];
    const float* nw     = (const float*)d_in[6];
    float* out = (float*)d_out;

    char* ws = (char*)d_ws;
    __hip_bfloat16* xq = (__hip_bfloat16*)ws;                    // 67108864 B (NHWC bf16)
    __hip_bfloat16* w2 = (__hip_bfloat16*)(ws + 67108864);       //  4718592 B
    float* s     = (float*)(ws + 71827456);                      //    32768 B
    float* demod = (float*)(ws + 71860224);                      //    32768 B
    float* wsq   = (float*)(ws + 71892992);                      //  1048576 B
    float* zbuf  = (float*)(ws + 72941568);                      //      256 B (zero page)

    static int lds_set = 0;
    if (!lds_set) {
        (void)hipFuncSetAttribute((const void*)conv_kernel,
                                  hipFuncAttributeMaxDynamicSharedMemorySize, 131072);
        lds_set = 1;
    }

    style_kernel<<<dim3(2, 16), 256, 0, stream>>>(w, lin_w, lin_b, s);
    prep_weights<<<512, 256, 0, stream>>>(conv_w, w2, wsq, zbuf);
    demod_kernel<<<dim3(2, 16), 256, 0, stream>>>(wsq, s, demod);
    upsample_mod_kernel<<<dim3(4, 16, 16), 256, 0, stream>>>(x, s, xq);
    conv_kernel<<<512, 512, 131072, stream>>>(xq, w2, demod, noise, nw, out,
                                              (const __hip_bfloat16*)zbuf);
}

// Round 3
// 345.426 us; speedup vs baseline: 1.2898x; 1.0203x over previous
//
#include <hip/hip_runtime.h>
#include <hip/hip_bf16.h>

#define B_ 16
#define CIN_ 512
#define COUT_ 512
#define SDIM_ 512
#define HIN_ 32
#define WIN_ 32
#define HOUT_ 64
#define WOUT_ 64

#define LIN_SCALE_C 0.044194173824159216f
#define CONV_SCALE_C 0.014731391274719742f

typedef short short8 __attribute__((ext_vector_type(8)));
typedef float f32x4 __attribute__((ext_vector_type(4)));

typedef const __attribute__((address_space(1))) void* gptr_t;
typedef __attribute__((address_space(3))) void* sptr_t;

__device__ __forceinline__ void glds16(const void* g, void* l) {
    __builtin_amdgcn_global_load_lds((gptr_t)g, (sptr_t)l, 16, 0, 0);
}

// ---------------- style: s[b,i] = LIN_SCALE * dot(w[b,:], lin_w[i,:]) + lin_b[i]
__global__ void style_kernel(const float* __restrict__ w, const float* __restrict__ lin_w,
                             const float* __restrict__ lin_b, float* __restrict__ s) {
    const int i = blockIdx.x * 256 + threadIdx.x;   // 0..511
    const int b = blockIdx.y;
    const float* wr = w + b * SDIM_;
    const float* lw = lin_w + i * SDIM_;
    float acc = 0.f;
    #pragma unroll 4
    for (int j = 0; j < SDIM_; ++j) acc += wr[j] * lw[j];
    s[b * CIN_ + i] = acc * LIN_SCALE_C + lin_b[i];
}

// ---------------- weights: w2[o][kk][i] = bf16(conv_w[o][i][kk]*CS); wsq[o][i] = sum_kk wk^2
__global__ void prep_weights(const float* __restrict__ conv_w, __hip_bfloat16* __restrict__ w2,
                             float* __restrict__ wsq, float* __restrict__ zbuf) {
    const int o = blockIdx.x;
    for (int i = threadIdx.x; i < CIN_; i += 256) {
        const float* src = conv_w + (o * CIN_ + i) * 9;
        float ss = 0.f;
        #pragma unroll
        for (int kk = 0; kk < 9; ++kk) {
            float v = src[kk] * CONV_SCALE_C;
            ss += v * v;
            w2[o * 4608 + kk * 512 + i] = __float2bfloat16(v);
        }
        wsq[o * CIN_ + i] = ss;
    }
    if (blockIdx.x == 0 && threadIdx.x < 64) zbuf[threadIdx.x] = 0.f;  // zero page for OOB halo
}

// ---------------- demod[b,o] = 1/sqrt(sum_i wsq[o,i]*s[b,i]^2 + eps)
__global__ void demod_kernel(const float* __restrict__ wsq, const float* __restrict__ s,
                             float* __restrict__ demod) {
    const int o = blockIdx.x * 256 + threadIdx.x;
    const int b = blockIdx.y;
    const float* sr = s + b * CIN_;
    const float* wr = wsq + o * CIN_;
    float acc = 0.f;
    #pragma unroll 4
    for (int i = 0; i < CIN_; ++i) { float sv = sr[i]; acc += wr[i] * sv * sv; }
    demod[b * COUT_ + o] = 1.0f / sqrtf(acc + 1e-8f);
}

// ---------------- bilinear 2x upsample + modulate, NCHW fp32 -> NHWC bf16
__global__ void upsample_mod_kernel(const float* __restrict__ x, const float* __restrict__ s,
                                    __hip_bfloat16* __restrict__ xq) {
    __shared__ float xs[10 * 32 * 33];  // [row 10][col 32][ch 33-padded]
    const int ht = blockIdx.x;          // 0..3  -> 16 output rows
    const int ct = blockIdx.y;          // 0..15 -> 32 channels
    const int b  = blockIdx.z;
    const int tid = threadIdx.x;
    const int ho0 = ht * 16, h0 = ht * 8, c0 = ct * 32;

    for (int idx = tid; idx < 10240; idx += 256) {
        int ch = idx / 320; int rem = idx - ch * 320;
        int rr = rem >> 5;  int col = rem & 31;
        int srow = h0 - 1 + rr; srow = min(max(srow, 0), 31);
        xs[(rr * 32 + col) * 33 + ch] = x[((b * CIN_ + c0 + ch) * HIN_ + srow) * WIN_ + col];
    }
    __syncthreads();

    for (int e = tid; e < 32768; e += 256) {
        int c = e & 31; int rest = e >> 5; int wo = rest & 63; int hr = rest >> 6;
        int ri0 = (hr + (hr & 1)) >> 1;
        float wlo_h = (hr & 1) ? 0.75f : 0.25f;
        int clo = (wo - 2 + (wo & 1)) >> 1;
        float wlo_w = (wo & 1) ? 0.75f : 0.25f;
        int chi = min(clo + 1, 31); clo = max(clo, 0);
        float v0 = xs[(ri0 * 32 + clo) * 33 + c];
        float v1 = xs[(ri0 * 32 + chi) * 33 + c];
        float v2 = xs[((ri0 + 1) * 32 + clo) * 33 + c];
        float v3 = xs[((ri0 + 1) * 32 + chi) * 33 + c];
        float rlo = wlo_w * v0 + (1.f - wlo_w) * v1;
        float rhi = wlo_w * v2 + (1.f - wlo_w) * v3;
        float val = (wlo_h * rlo + (1.f - wlo_h) * rhi) * s[b * CIN_ + c0 + c];
        xq[(((b * HOUT_ + ho0 + hr) * WOUT_) + wo) * CIN_ + c0 + c] = __float2bfloat16(val);
    }
}

// ---------------- implicit-GEMM conv, 256x256 tile, BK=32, 4-deep LDS ring, counted vmcnt
// LDS chunk swizzle: logical chunk c (16B) of row R stored at phys chunk c ^ ((R>>1)&3).
// glds16 dest stays LINEAR; the involution is applied to the global SOURCE chunk and
// to the frag-read address (both-sides rule, m201 stage_rc pattern).
__global__ __launch_bounds__(512)
void conv_kernel(const __hip_bfloat16* __restrict__ xq,
                 const __hip_bfloat16* __restrict__ w2,
                 const float* __restrict__ demod,
                 const float* __restrict__ noise,
                 const float* __restrict__ nw_p,
                 float* __restrict__ out,
                 const __hip_bfloat16* __restrict__ zbuf) {
    extern __shared__ __hip_bfloat16 smem[];
    __hip_bfloat16* As = smem;           // 4 slots x [256][32] = 4 x 8192 elems (64 KB)
    __hip_bfloat16* Bs = smem + 32768;   // 4 slots x [256][32]                  (64 KB)

    const int bid = blockIdx.x;
    const int swz = (bid & 7) * 64 + (bid >> 3);
    const int b  = swz >> 5;          // 16 batches
    const int mt = (swz >> 4) & 1;    // 2 cout tiles
    const int nt = swz & 15;          // 16 pixel tiles (4 rows x 64 cols each)
    const int o0 = mt * 256;
    const int p0 = nt * 256;

    const int tid  = threadIdx.x;
    const int lane = tid & 63;
    const int wave = tid >> 6;
    const int wm = wave >> 2, wn = wave & 3;   // 2M x 4N waves, each 128x64 out

    // ---- staging coords: 4 threads per row (64B); SOURCE chunk is swizzle-permuted
    const int srow = tid >> 2;            // 0..127
    const int schk = (((tid & 3) ^ ((tid >> 3) & 3))) * 8;   // swizzled source chunk (elements)
    const int aoff = (o0 + srow) * 4608 + schk;              // + h*128*4608 + u*32
    const int brow_lo = nt * 4 + (srow >> 6);                // + h*2 + dh
    const int bcol = srow & 63;
    const int sdst = tid * 8;             // LINEAR dest: + slot*8192 + h*4096 (elements)

    // ---- frag read offsets (elements, within slot), swizzled chunk
    const int lrow = lane & 15;
    const int pko = ((lane >> 4) ^ ((lrow >> 1) & 3)) * 8;   // phys chunk of logical k-chunk
    const int ard = (wm * 128 + lrow) * 32 + pko;            // + m*512
    const int brd = (wn * 64 + lrow) * 32 + pko;             // + n*512

    f32x4 acc[8][4] = {};

    #define STAGE_A(u, h) \
        glds16(w2 + aoff + (h) * 589824 + (u) * 32, As + (((u) & 3) << 13) + ((h) << 12) + sdst)
    #define STAGE_B(u, h, dh, dw, i0) do { \
        int rr_ = brow_lo + (h) * 2 + (dh); \
        int cc_ = bcol + (dw); \
        bool v_ = ((unsigned)rr_ < 64u) && ((unsigned)cc_ < 64u); \
        const __hip_bfloat16* src_ = v_ ? xq + ((b * 64 + rr_) * 64 + cc_) * 512 + (i0) + schk : zbuf; \
        glds16(src_, Bs + (((u) & 3) << 13) + ((h) << 12) + sdst); \
    } while (0)

    // prologue: stage tiles 0 and 1 (both in kk=0: dh=dw=-1)
    STAGE_A(0, 0); STAGE_A(0, 1); STAGE_B(0, 0, -1, -1, 0);  STAGE_B(0, 1, -1, -1, 0);
    STAGE_A(1, 0); STAGE_A(1, 1); STAGE_B(1, 0, -1, -1, 32); STAGE_B(1, 1, -1, -1, 32);
    asm volatile("s_waitcnt vmcnt(4)" ::: "memory");   // tile 0 fully landed
    __builtin_amdgcn_s_barrier();

    #pragma unroll 4
    for (int t = 0; t < 144; ++t) {
        const int slot = (t & 3) << 13;

        short8 a[8], bf[4];
        #pragma unroll
        for (int m = 0; m < 8; ++m)
            a[m] = *(const short8*)(As + slot + ard + m * 512);
        #pragma unroll
        for (int n = 0; n < 4; ++n)
            bf[n] = *(const short8*)(Bs + slot + brd + n * 512);

        const int u = t + 2;
        if (u < 144) {
            const int kk = u >> 4;
            const int i0 = (u & 15) << 5;
            const int kd = (kk * 11) >> 5;       // kk/3
            const int dh = kd - 1, dw = kk - kd * 3 - 1;
            STAGE_A(u, 0); STAGE_A(u, 1);
            STAGE_B(u, 0, dh, dw, i0); STAGE_B(u, 1, dh, dw, i0);
        }

        // counted wait: forces tile t+1 (staged last iter) complete; leaves this
        // iter's 4 stages (tile t+2) in flight. Tail: drain.
        if (t < 142) asm volatile("s_waitcnt vmcnt(4)" ::: "memory");
        else         asm volatile("s_waitcnt vmcnt(0)" ::: "memory");
        __builtin_amdgcn_s_barrier();

        __builtin_amdgcn_s_setprio(1);
        #pragma unroll
        for (int m = 0; m < 8; ++m)
            #pragma unroll
            for (int n = 0; n < 4; ++n)
                acc[m][n] = __builtin_amdgcn_mfma_f32_16x16x32_bf16(a[m], bf[n], acc[m][n], 0, 0, 0);
        __builtin_amdgcn_s_setprio(0);
    }
    #undef STAGE_A
    #undef STAGE_B

    // epilogue: demod * acc + nw*noise, leaky-relu * sqrt(2)
    const float nwv = nw_p[0];
    const int colp = lane & 15;
    const int rgrp = (lane >> 4) * 4;
    float nz[4];
    #pragma unroll
    for (int ni = 0; ni < 4; ++ni)
        nz[ni] = noise[b * 4096 + p0 + wn * 64 + ni * 16 + colp] * nwv;
    #pragma unroll
    for (int mi = 0; mi < 8; ++mi) {
        const int obase = o0 + wm * 128 + mi * 16 + rgrp;
        float dm[4];
        #pragma unroll
        for (int j = 0; j < 4; ++j) dm[j] = demod[b * COUT_ + obase + j];
        #pragma unroll
        for (int ni = 0; ni < 4; ++ni) {
            const int pix = p0 + wn * 64 + ni * 16 + colp;
            #pragma unroll
            for (int j = 0; j < 4; ++j) {
                float v = acc[mi][ni][j] * dm[j] + nz[ni];
                v = (v >= 0.f ? v : 0.2f * v) * 1.4142135623730951f;
                out[(b * COUT_ + obase + j) * 4096 + pix] = v;
            }
        }
    }
}

extern "C" void kernel_launch(void* const* d_in, const int* in_sizes, int n_in,
                              void* d_out, int out_size, void* d_ws, size_t ws_size,
                              hipStream_t stream) {
    const float* x      = (const float*)d_in[0];
    const float* w      = (const float*)d_in[1];
    const float* noise  = (const float*)d_in[2];
    const float* lin_w  = (const float*)d_in[3];
    const float* lin_b  = (const float*)d_in[4];
    const float* conv_w = (const float*)d_in[5];
    const float* nw     = (const float*)d_in[6];
    float* out = (float*)d_out;

    char* ws = (char*)d_ws;
    __hip_bfloat16* xq = (__hip_bfloat16*)ws;                    // 67108864 B (NHWC bf16)
    __hip_bfloat16* w2 = (__hip_bfloat16*)(ws + 67108864);       //  4718592 B
    float* s     = (float*)(ws + 71827456);                      //    32768 B
    float* demod = (float*)(ws + 71860224);                      //    32768 B
    float* wsq   = (float*)(ws + 71892992);                      //  1048576 B
    float* zbuf  = (float*)(ws + 72941568);                      //      256 B (zero page)

    static int lds_set = 0;
    if (!lds_set) {
        (void)hipFuncSetAttribute((const void*)conv_kernel,
                                  hipFuncAttributeMaxDynamicSharedMemorySize, 131072);
        lds_set = 1;
    }

    style_kernel<<<dim3(2, 16), 256, 0, stream>>>(w, lin_w, lin_b, s);
    prep_weights<<<512, 256, 0, stream>>>(conv_w, w2, wsq, zbuf);
    demod_kernel<<<dim3(2, 16), 256, 0, stream>>>(wsq, s, demod);
    upsample_mod_kernel<<<dim3(4, 16, 16), 256, 0, stream>>>(x, s, xq);
    conv_kernel<<<512, 512, 131072, stream>>>(xq, w2, demod, noise, nw, out,
                                              (const __hip_bfloat16*)zbuf);
}